// Round 1
// baseline (14000.243 us; speedup 1.0000x reference)
//
#include <hip/hip_runtime.h>
#include <hip/hip_bf16.h>

// Masked LSTM, T=512 B=64 D=512 H=512.
// Phase A: x_proj[m][g] = inputs[m][:] . W_ih[g][:] + b_ih[g] + b_hh[g]   (fp32 tiled GEMM)
// Phase B: persistent recurrence kernel. 8 groups x 32 blocks (256 blocks, 1/CU via LDS),
//          group g owns batches [8g,8g+8); block rank owns 16 h-dims (64 gate rows),
//          W_hh slice resident in LDS (128KB), h exchanged via double-buffered global,
//          one agent-scope group barrier per step.

#define T_DIM 512
#define B_DIM 64
#define D_DIM 512
#define H_DIM 512
#define G_DIM 2048              // 4*H
#define M_DIM (T_DIM * B_DIM)   // 32768

#define NGROUP 8
#define BPG 32                  // blocks per group
#define NBLK (NGROUP * BPG)     // 256
#define NTHR 512
#define JPB 16                  // h-dims per block (H/BPG)
#define BPGRP 8                 // batches per group (B/NGROUP)
#define HL_STRIDE 520           // h LDS row stride (512 + 8 pad, 16B-aligned)

__device__ __forceinline__ float sigf(float x) { return 1.0f / (1.0f + __expf(-x)); }
__device__ __forceinline__ float tanhfast(float x) { return 2.0f / (1.0f + __expf(-2.0f * x)) - 1.0f; }

// ---------------------------------------------------------------- Phase A
template <typename OUT>
__global__ __launch_bounds__(256) void xproj_gemm(
    const float* __restrict__ A, const float* __restrict__ W,
    const float* __restrict__ b1, const float* __restrict__ b2,
    OUT* __restrict__ C) {
  __shared__ __align__(16) float As[16][68];   // [k][m], pad 4 -> conflict-free
  __shared__ __align__(16) float Bs[16][68];   // [k][n]
  const int tid = threadIdx.x;
  const int bm = blockIdx.x, bn = blockIdx.y;
  const int lr = tid >> 2, lk = tid & 3;       // loader: row 0..63, k-quad 0..3
  const int tx = tid & 15, ty = tid >> 4;      // compute: 16x16, 4x4 microtile
  const float* Ap = A + (size_t)(bm * 64 + lr) * D_DIM + lk * 4;
  const float* Wp = W + (size_t)(bn * 64 + lr) * D_DIM + lk * 4;
  float acc[4][4] = {};
  for (int k0 = 0; k0 < D_DIM; k0 += 16) {
    float4 av = *(const float4*)(Ap + k0);
    float4 wv = *(const float4*)(Wp + k0);
    __syncthreads();  // protect previous iteration's reads
    As[lk * 4 + 0][lr] = av.x; As[lk * 4 + 1][lr] = av.y;
    As[lk * 4 + 2][lr] = av.z; As[lk * 4 + 3][lr] = av.w;
    Bs[lk * 4 + 0][lr] = wv.x; Bs[lk * 4 + 1][lr] = wv.y;
    Bs[lk * 4 + 2][lr] = wv.z; Bs[lk * 4 + 3][lr] = wv.w;
    __syncthreads();
#pragma unroll
    for (int kk = 0; kk < 16; ++kk) {
      float4 a = *(const float4*)&As[kk][ty * 4];
      float4 b = *(const float4*)&Bs[kk][tx * 4];
      acc[0][0] += a.x * b.x; acc[0][1] += a.x * b.y; acc[0][2] += a.x * b.z; acc[0][3] += a.x * b.w;
      acc[1][0] += a.y * b.x; acc[1][1] += a.y * b.y; acc[1][2] += a.y * b.z; acc[1][3] += a.y * b.w;
      acc[2][0] += a.z * b.x; acc[2][1] += a.z * b.y; acc[2][2] += a.z * b.z; acc[2][3] += a.z * b.w;
      acc[3][0] += a.w * b.x; acc[3][1] += a.w * b.y; acc[3][2] += a.w * b.z; acc[3][3] += a.w * b.w;
    }
  }
  const int gm = bm * 64 + ty * 4;
  const int gn = bn * 64 + tx * 4;
  float4 bv1 = *(const float4*)&b1[gn];
  float4 bv2 = *(const float4*)&b2[gn];
  float bias0 = bv1.x + bv2.x, bias1 = bv1.y + bv2.y, bias2 = bv1.z + bv2.z, bias3 = bv1.w + bv2.w;
#pragma unroll
  for (int i = 0; i < 4; ++i) {
    OUT* cp = C + (size_t)(gm + i) * G_DIM + gn;
    cp[0] = (OUT)(acc[i][0] + bias0);
    cp[1] = (OUT)(acc[i][1] + bias1);
    cp[2] = (OUT)(acc[i][2] + bias2);
    cp[3] = (OUT)(acc[i][3] + bias3);
  }
}

// ---------------------------------------------------------------- group barrier
__device__ __forceinline__ void gbarrier(int* cnt, int* flg, int target) {
  __syncthreads();                 // all waves drain their own mem ops
  if (threadIdx.x == 0) {
    __threadfence();               // agent-scope release of this block's writes
    int prev = __hip_atomic_fetch_add(cnt, 1, __ATOMIC_ACQ_REL, __HIP_MEMORY_SCOPE_AGENT);
    if (prev == BPG - 1) {
      __hip_atomic_store(cnt, 0, __ATOMIC_RELAXED, __HIP_MEMORY_SCOPE_AGENT);
      __hip_atomic_store(flg, target, __ATOMIC_RELEASE, __HIP_MEMORY_SCOPE_AGENT);
    } else {
      while (__hip_atomic_load(flg, __ATOMIC_ACQUIRE, __HIP_MEMORY_SCOPE_AGENT) < target) {
        __builtin_amdgcn_s_sleep(1);
      }
    }
    __threadfence();               // agent-scope acquire before anyone reads h
  }
  __syncthreads();
}

// ---------------------------------------------------------------- Phase B
template <typename XP>
__global__ __launch_bounds__(NTHR) void lstm_seq(
    const XP* __restrict__ xproj, const float* __restrict__ mask,
    const float* __restrict__ h0, const float* __restrict__ Whh,
    float* __restrict__ out, float* __restrict__ hbuf,
    int* bar_cnt_base, int* bar_flag_base) {
  extern __shared__ float smem[];
  float* Wl = smem;                        // [k][r] 512*64 floats = 128KB
  float* hl = Wl + 512 * 64;               // [b][k] 8*520 floats (aliased as partials)
  float* gl = hl + BPGRP * HL_STRIDE;      // gates [b*64 + jl*4 + q], 512 floats
  float* cl = gl + 512;                    // c state [b*16 + jl], 128 floats

  const int tid = threadIdx.x;
  const int blk = blockIdx.x;
  const int grp = blk & 7;                 // group == XCD (dispatch heuristic)
  const int rank = blk >> 3;               // 0..31 within group
  const int bbase = grp * BPGRP;
  const int jbase = rank * JPB;
  int* cnt = (int*)((char*)bar_cnt_base + grp * 128);
  int* flg = (int*)((char*)bar_flag_base + grp * 128);

  // Load W_hh slice into LDS, k-major: Wl[k*64 + r], r = q*16 + jl -> global row q*512+jbase+jl
  for (int idx = tid; idx < 64 * 128; idx += NTHR) {
    int r = idx >> 7;
    int k4 = (idx & 127) << 2;
    int q = r >> 4, jl = r & 15;
    int grow = q * H_DIM + jbase + jl;
    float4 w = *(const float4*)(Whh + (size_t)grow * H_DIM + k4);
    Wl[(k4 + 0) * 64 + r] = w.x;
    Wl[(k4 + 1) * 64 + r] = w.y;
    Wl[(k4 + 2) * 64 + r] = w.z;
    Wl[(k4 + 3) * 64 + r] = w.w;
  }

  // Elementwise-thread constants + init h_buf[0] slice and c state (c0 = h0 per reference)
  const int eb = tid >> 4, ejl = tid & 15;   // tid<128: (batch, h-dim)
  float h0v = 0.0f, c0v = 0.0f;
  if (tid < 128) {
    int bglob = bbase + eb;
    int jglob = jbase + ejl;
    h0v = h0[bglob * H_DIM + jglob];
    c0v = h0v;
    cl[eb * JPB + ejl] = c0v;
    hbuf[bglob * H_DIM + jglob] = h0v;
  }
  gbarrier(cnt, flg, 1);

  const int r = tid & 63;        // gate-row within block
  const int kq = tid >> 6;       // k-slice (wave id), 64 k each
  const int k0base = kq * 64;

  for (int ts = 0; ts < T_DIM; ++ts) {
    const float* cur = hbuf + (ts & 1) * (B_DIM * H_DIM);
    float* nxt = hbuf + ((ts + 1) & 1) * (B_DIM * H_DIM);

    // stage h (8 batches x 512) into LDS [b][k]
    for (int idx = tid; idx < BPGRP * 128; idx += NTHR) {
      int b = idx >> 7;
      int k4 = (idx & 127) << 2;
      float4 h4 = *(const float4*)(cur + (bbase + b) * H_DIM + k4);
      *(float4*)(hl + b * HL_STRIDE + k4) = h4;
    }
    // prefetch x_proj + mask early (used in epilogue)
    float xpv0 = 0.f, xpv1 = 0.f, xpv2 = 0.f, xpv3 = 0.f, mval = 1.f;
    if (tid < 128) {
      int bglob = bbase + eb;
      int jglob = jbase + ejl;
      const XP* xb = xproj + ((size_t)ts * B_DIM + bglob) * G_DIM + jglob;
      xpv0 = (float)xb[0];
      xpv1 = (float)xb[512];
      xpv2 = (float)xb[1024];
      xpv3 = (float)xb[1536];
      mval = mask[ts * B_DIM + bglob];
    }
    __syncthreads();

    // partial GEMM: acc[b] = sum_{k in slice} W[k][r] * h[b][k]
    float acc[BPGRP] = {0.f, 0.f, 0.f, 0.f, 0.f, 0.f, 0.f, 0.f};
#pragma unroll 4
    for (int k = k0base; k < k0base + 64; k += 4) {
      float w0 = Wl[(k + 0) * 64 + r];
      float w1 = Wl[(k + 1) * 64 + r];
      float w2 = Wl[(k + 2) * 64 + r];
      float w3 = Wl[(k + 3) * 64 + r];
#pragma unroll
      for (int b = 0; b < BPGRP; ++b) {
        float4 h4 = *(const float4*)(hl + b * HL_STRIDE + k);
        acc[b] += w0 * h4.x + w1 * h4.y + w2 * h4.z + w3 * h4.w;
      }
    }
    __syncthreads();               // h reads done; reuse hl as partial buffer
    float* part = hl;
#pragma unroll
    for (int b = 0; b < BPGRP; ++b) part[kq * 512 + b * 64 + r] = acc[b];
    __syncthreads();
    {
      // reduce 8 partials -> gates, store i,f,g,o adjacent per (b, jl)
      int r2 = tid & 63, b2 = tid >> 6;
      float s = 0.f;
#pragma unroll
      for (int q8 = 0; q8 < 8; ++q8) s += part[q8 * 512 + b2 * 64 + r2];
      gl[b2 * 64 + (r2 & 15) * 4 + (r2 >> 4)] = s;
    }
    __syncthreads();

    if (tid < 128) {
      int bglob = bbase + eb;
      int jglob = jbase + ejl;
      float4 g4 = *(const float4*)&gl[eb * 64 + ejl * 4];
      float iv = sigf(g4.x + xpv0);
      float fv = sigf(g4.y + xpv1);
      float gv = tanhfast(g4.z + xpv2);
      float ov = sigf(g4.w + xpv3);
      float c_old = cl[eb * JPB + ejl];
      float c_new = fv * c_old + iv * gv;
      float h_new = ov * tanhfast(c_new);
      h_new = h_new * mval + h0v * (1.0f - mval);
      c_new = c_new * mval + c0v * (1.0f - mval);
      cl[eb * JPB + ejl] = c_new;
      nxt[bglob * H_DIM + jglob] = h_new;
      out[((size_t)ts * B_DIM + bglob) * H_DIM + jglob] = h_new;
      if (ts == T_DIM - 1) {
        out[(size_t)T_DIM * B_DIM * H_DIM + bglob * H_DIM + jglob] = h_new;
        out[(size_t)T_DIM * B_DIM * H_DIM + B_DIM * H_DIM + bglob * H_DIM + jglob] = c_new;
      }
    }
    gbarrier(cnt, flg, ts + 2);
  }
}

// ---------------------------------------------------------------- launch
extern "C" void kernel_launch(void* const* d_in, const int* in_sizes, int n_in,
                              void* d_out, int out_size, void* d_ws, size_t ws_size,
                              hipStream_t stream) {
  const float* inputs = (const float*)d_in[0];
  const float* maskp  = (const float*)d_in[1];
  const float* h0     = (const float*)d_in[2];
  const float* W_ih   = (const float*)d_in[3];
  const float* W_hh   = (const float*)d_in[4];
  const float* b_ih   = (const float*)d_in[5];
  const float* b_hh   = (const float*)d_in[6];
  float* out = (float*)d_out;

  char* ws = (char*)d_ws;
  int* bar_cnt  = (int*)ws;              // 8 counters, 128B apart
  int* bar_flag = (int*)(ws + 2048);     // 8 flags, 128B apart
  float* hbuf = (float*)(ws + 4096);     // double buffer: 2 * 64*512 f32 = 256KB
  char* xp = ws + 4096 + (size_t)2 * B_DIM * H_DIM * sizeof(float);  // 266240, 256-aligned
  size_t base = 4096 + (size_t)2 * B_DIM * H_DIM * sizeof(float);
  size_t need_f32  = base + (size_t)M_DIM * G_DIM * sizeof(float);
  size_t need_bf16 = base + (size_t)M_DIM * G_DIM * sizeof(__hip_bfloat16);

  hipMemsetAsync(d_ws, 0, 4096, stream);  // zero barrier state (ws re-poisoned each call)

  dim3 gridA(M_DIM / 64, G_DIM / 64);
  size_t ldsB = (size_t)(512 * 64 + BPGRP * HL_STRIDE + 512 + 128) * sizeof(float);  // 150272 B

  if (ws_size >= need_f32) {
    xproj_gemm<float><<<gridA, 256, 0, stream>>>(inputs, W_ih, b_ih, b_hh, (float*)xp);
    lstm_seq<float><<<NBLK, NTHR, ldsB, stream>>>((const float*)xp, maskp, h0, W_hh,
                                                  out, hbuf, bar_cnt, bar_flag);
  } else {
    // fallback: bf16 x_proj (halves workspace); recurrence stays fp32
    xproj_gemm<__hip_bfloat16><<<gridA, 256, 0, stream>>>(inputs, W_ih, b_ih, b_hh,
                                                          (__hip_bfloat16*)xp);
    lstm_seq<__hip_bfloat16><<<NBLK, NTHR, ldsB, stream>>>((const __hip_bfloat16*)xp, maskp,
                                                           h0, W_hh, out, hbuf, bar_cnt, bar_flag);
  }
  (void)in_sizes; (void)n_in; (void)out_size; (void)need_bf16;
}

// Round 2
// 4484.053 us; speedup vs baseline: 3.1222x; 3.1222x over previous
//
#include <hip/hip_runtime.h>
#include <hip/hip_bf16.h>

// Masked LSTM, T=512 B=64 D=512 H=512.
// Phase A: x_proj = inputs @ W_ih^T + (b_ih + b_hh), fp32 VALU GEMM, stored bf16.
// Phase B: persistent recurrence. 8 groups x 32 blocks; group g owns batches [8g,8g+8);
//          block rank owns 16 h-dims (64 gate rows); W_hh slice resident in LDS (128KB).
//          Cross-block h exchange + barrier use RELAXED AGENT-scope atomics only
//          (global_* sc1: per-access L3-coherent, NO buffer_wbl2/buffer_inv cache
//          flushes -- agent-scope acquire/release FENCES on multi-XCD gfx9 writeback/
//          invalidate the entire L2 and cost ~10s of us/step; relaxed flagged accesses
//          don't). Ordering: __syncthreads() drains vmcnt(0) => h-stores are at the
//          coherence point before the arrival-slot store; consumers poll slots then load.

#define T_DIM 512
#define B_DIM 64
#define D_DIM 512
#define H_DIM 512
#define G_DIM 2048              // 4*H
#define M_DIM (T_DIM * B_DIM)   // 32768

#define NGROUP 8
#define BPG 32                  // blocks per group
#define NBLK (NGROUP * BPG)     // 256
#define NTHR 512
#define JPB 16                  // h-dims per block (H/BPG)
#define BPGRP 8                 // batches per group (B/NGROUP)
#define HL_STRIDE 520           // h LDS row stride (512 + 8 pad)

#define AT_LD_F(p)    __hip_atomic_load((p), __ATOMIC_RELAXED, __HIP_MEMORY_SCOPE_AGENT)
#define AT_ST_F(p, v) __hip_atomic_store((p), (v), __ATOMIC_RELAXED, __HIP_MEMORY_SCOPE_AGENT)
#define AT_LD_I(p)    __hip_atomic_load((p), __ATOMIC_RELAXED, __HIP_MEMORY_SCOPE_AGENT)
#define AT_ST_I(p, v) __hip_atomic_store((p), (v), __ATOMIC_RELAXED, __HIP_MEMORY_SCOPE_AGENT)

__device__ __forceinline__ float sigf(float x) { return 1.0f / (1.0f + __expf(-x)); }
__device__ __forceinline__ float tanhfast(float x) { return 2.0f / (1.0f + __expf(-2.0f * x)) - 1.0f; }

// ---------------------------------------------------------------- Phase A
template <typename OUT>
__global__ __launch_bounds__(256) void xproj_gemm(
    const float* __restrict__ A, const float* __restrict__ W,
    const float* __restrict__ b1, const float* __restrict__ b2,
    OUT* __restrict__ C) {
  __shared__ __align__(16) float As[16][68];
  __shared__ __align__(16) float Bs[16][68];
  const int tid = threadIdx.x;
  const int bm = blockIdx.x, bn = blockIdx.y;
  const int lr = tid >> 2, lk = tid & 3;
  const int tx = tid & 15, ty = tid >> 4;
  const float* Ap = A + (size_t)(bm * 64 + lr) * D_DIM + lk * 4;
  const float* Wp = W + (size_t)(bn * 64 + lr) * D_DIM + lk * 4;
  float acc[4][4] = {};
  for (int k0 = 0; k0 < D_DIM; k0 += 16) {
    float4 av = *(const float4*)(Ap + k0);
    float4 wv = *(const float4*)(Wp + k0);
    __syncthreads();
    As[lk * 4 + 0][lr] = av.x; As[lk * 4 + 1][lr] = av.y;
    As[lk * 4 + 2][lr] = av.z; As[lk * 4 + 3][lr] = av.w;
    Bs[lk * 4 + 0][lr] = wv.x; Bs[lk * 4 + 1][lr] = wv.y;
    Bs[lk * 4 + 2][lr] = wv.z; Bs[lk * 4 + 3][lr] = wv.w;
    __syncthreads();
#pragma unroll
    for (int kk = 0; kk < 16; ++kk) {
      float4 a = *(const float4*)&As[kk][ty * 4];
      float4 b = *(const float4*)&Bs[kk][tx * 4];
      acc[0][0] += a.x * b.x; acc[0][1] += a.x * b.y; acc[0][2] += a.x * b.z; acc[0][3] += a.x * b.w;
      acc[1][0] += a.y * b.x; acc[1][1] += a.y * b.y; acc[1][2] += a.y * b.z; acc[1][3] += a.y * b.w;
      acc[2][0] += a.z * b.x; acc[2][1] += a.z * b.y; acc[2][2] += a.z * b.z; acc[2][3] += a.z * b.w;
      acc[3][0] += a.w * b.x; acc[3][1] += a.w * b.y; acc[3][2] += a.w * b.z; acc[3][3] += a.w * b.w;
    }
  }
  const int gm = bm * 64 + ty * 4;
  const int gn = bn * 64 + tx * 4;
  float4 bv1 = *(const float4*)&b1[gn];
  float4 bv2 = *(const float4*)&b2[gn];
  float bias0 = bv1.x + bv2.x, bias1 = bv1.y + bv2.y, bias2 = bv1.z + bv2.z, bias3 = bv1.w + bv2.w;
#pragma unroll
  for (int i = 0; i < 4; ++i) {
    OUT* cp = C + (size_t)(gm + i) * G_DIM + gn;
    cp[0] = (OUT)(acc[i][0] + bias0);
    cp[1] = (OUT)(acc[i][1] + bias1);
    cp[2] = (OUT)(acc[i][2] + bias2);
    cp[3] = (OUT)(acc[i][3] + bias3);
  }
}

// ---------------------------------------------------------------- group barrier
// Per-block arrival slots (monotone step number, relaxed agent stores, no RMW).
// Wave 0 polls all 32 slots of its group; no fences anywhere.
__device__ __forceinline__ void gbarrier(int* slots, int rank, int target) {
  __syncthreads();   // emits s_waitcnt vmcnt(0): this block's sc1 h-stores are at L3
  const int tid = threadIdx.x;
  if (tid == 0) AT_ST_I(&slots[rank], target);
  if (tid < 64) {
    int v;
    do {
      v = (tid < BPG) ? AT_LD_I(&slots[tid]) : target;
      if (__all(v >= target)) break;
      __builtin_amdgcn_s_sleep(2);
    } while (true);
  }
  __syncthreads();
  __asm__ volatile("" ::: "memory");   // keep h-loads after the poll
}

// ---------------------------------------------------------------- Phase B
template <typename XP>
__global__ __launch_bounds__(NTHR) void lstm_seq(
    const XP* __restrict__ xproj, const float* __restrict__ mask,
    const float* __restrict__ h0, const float* __restrict__ Whh,
    float* __restrict__ out, float* __restrict__ hbuf,
    int* slot_base) {
  extern __shared__ float smem[];
  float* Wl = smem;                        // [k][r] 512*64 floats = 128KB
  float* hl = Wl + 512 * 64;               // [b][k] 8*520 floats (aliased as partials)
  float* gl = hl + BPGRP * HL_STRIDE;      // gates, 512 floats
  float* cl = gl + 512;                    // c state, 128 floats

  const int tid = threadIdx.x;
  const int blk = blockIdx.x;
  const int grp = blk & 7;
  const int rank = blk >> 3;
  const int bbase = grp * BPGRP;
  const int jbase = rank * JPB;
  int* slots = (int*)((char*)slot_base + grp * 128);

  // W_hh slice -> LDS, k-major: Wl[k*64 + r], r = q*16 + jl -> global row q*512+jbase+jl
  for (int idx = tid; idx < 64 * 128; idx += NTHR) {
    int r = idx >> 7;
    int k4 = (idx & 127) << 2;
    int q = r >> 4, jl = r & 15;
    int grow = q * H_DIM + jbase + jl;
    float4 w = *(const float4*)(Whh + (size_t)grow * H_DIM + k4);
    Wl[(k4 + 0) * 64 + r] = w.x;
    Wl[(k4 + 1) * 64 + r] = w.y;
    Wl[(k4 + 2) * 64 + r] = w.z;
    Wl[(k4 + 3) * 64 + r] = w.w;
  }

  const int eb = tid >> 4, ejl = tid & 15;   // tid<128: (batch, h-dim)
  float h0v = 0.0f, c0v = 0.0f;
  if (tid < 128) {
    int bglob = bbase + eb;
    int jglob = jbase + ejl;
    h0v = h0[bglob * H_DIM + jglob];
    c0v = h0v;
    cl[eb * JPB + ejl] = c0v;
    AT_ST_F(&hbuf[bglob * H_DIM + jglob], h0v);
  }
  gbarrier(slots, rank, 1);

  const int r = tid & 63;        // gate-row within block
  const int kq = tid >> 6;       // k-slice (wave id), 64 k each
  const int k0base = kq * 64;

  for (int ts = 0; ts < T_DIM; ++ts) {
    const float* cur = hbuf + (ts & 1) * (B_DIM * H_DIM);
    float* nxt = hbuf + ((ts + 1) & 1) * (B_DIM * H_DIM);

    // stage h (8 batches x 512) into LDS [b][k] -- sc1 loads from L3
    for (int idx = tid; idx < BPGRP * 128; idx += NTHR) {
      int b = idx >> 7;
      int k4 = (idx & 127) << 2;
      const float* src = cur + (bbase + b) * H_DIM + k4;
      float4 h4;
      h4.x = AT_LD_F(src + 0);
      h4.y = AT_LD_F(src + 1);
      h4.z = AT_LD_F(src + 2);
      h4.w = AT_LD_F(src + 3);
      *(float4*)(hl + b * HL_STRIDE + k4) = h4;
    }
    // prefetch x_proj + mask (plain loads; used in epilogue)
    float xpv0 = 0.f, xpv1 = 0.f, xpv2 = 0.f, xpv3 = 0.f, mval = 1.f;
    if (tid < 128) {
      int bglob = bbase + eb;
      int jglob = jbase + ejl;
      const XP* xb = xproj + ((size_t)ts * B_DIM + bglob) * G_DIM + jglob;
      xpv0 = (float)xb[0];
      xpv1 = (float)xb[512];
      xpv2 = (float)xb[1024];
      xpv3 = (float)xb[1536];
      mval = mask[ts * B_DIM + bglob];
    }
    __syncthreads();

    // partial GEMM: acc[b] = sum_{k in slice} W[k][r] * h[b][k]
    float acc[BPGRP] = {0.f, 0.f, 0.f, 0.f, 0.f, 0.f, 0.f, 0.f};
#pragma unroll 4
    for (int k = k0base; k < k0base + 64; k += 4) {
      float w0 = Wl[(k + 0) * 64 + r];
      float w1 = Wl[(k + 1) * 64 + r];
      float w2 = Wl[(k + 2) * 64 + r];
      float w3 = Wl[(k + 3) * 64 + r];
#pragma unroll
      for (int b = 0; b < BPGRP; ++b) {
        float4 h4 = *(const float4*)(hl + b * HL_STRIDE + k);
        acc[b] += w0 * h4.x + w1 * h4.y + w2 * h4.z + w3 * h4.w;
      }
    }
    __syncthreads();               // h reads done; reuse hl as partial buffer
    float* part = hl;
#pragma unroll
    for (int b = 0; b < BPGRP; ++b) part[kq * 512 + b * 64 + r] = acc[b];
    __syncthreads();
    {
      int r2 = tid & 63, b2 = tid >> 6;
      float s = 0.f;
#pragma unroll
      for (int q8 = 0; q8 < 8; ++q8) s += part[q8 * 512 + b2 * 64 + r2];
      gl[b2 * 64 + (r2 & 15) * 4 + (r2 >> 4)] = s;
    }
    __syncthreads();

    if (tid < 128) {
      int bglob = bbase + eb;
      int jglob = jbase + ejl;
      float4 g4 = *(const float4*)&gl[eb * 64 + ejl * 4];
      float iv = sigf(g4.x + xpv0);
      float fv = sigf(g4.y + xpv1);
      float gv = tanhfast(g4.z + xpv2);
      float ov = sigf(g4.w + xpv3);
      float c_old = cl[eb * JPB + ejl];
      float c_new = fv * c_old + iv * gv;
      float h_new = ov * tanhfast(c_new);
      h_new = h_new * mval + h0v * (1.0f - mval);
      c_new = c_new * mval + c0v * (1.0f - mval);
      cl[eb * JPB + ejl] = c_new;
      AT_ST_F(&nxt[bglob * H_DIM + jglob], h_new);   // sc1: visible at L3
      out[((size_t)ts * B_DIM + bglob) * H_DIM + jglob] = h_new;
      if (ts == T_DIM - 1) {
        out[(size_t)T_DIM * B_DIM * H_DIM + bglob * H_DIM + jglob] = h_new;
        out[(size_t)T_DIM * B_DIM * H_DIM + B_DIM * H_DIM + bglob * H_DIM + jglob] = c_new;
      }
    }
    gbarrier(slots, rank, ts + 2);
  }
}

// ---------------------------------------------------------------- launch
extern "C" void kernel_launch(void* const* d_in, const int* in_sizes, int n_in,
                              void* d_out, int out_size, void* d_ws, size_t ws_size,
                              hipStream_t stream) {
  const float* inputs = (const float*)d_in[0];
  const float* maskp  = (const float*)d_in[1];
  const float* h0     = (const float*)d_in[2];
  const float* W_ih   = (const float*)d_in[3];
  const float* W_hh   = (const float*)d_in[4];
  const float* b_ih   = (const float*)d_in[5];
  const float* b_hh   = (const float*)d_in[6];
  float* out = (float*)d_out;

  char* ws = (char*)d_ws;
  int* slot_base = (int*)ws;             // 8 groups x 32 int slots, 128B apart
  float* hbuf = (float*)(ws + 4096);     // double buffer: 2 * 64*512 f32 = 256KB
  char* xp = ws + 4096 + (size_t)2 * B_DIM * H_DIM * sizeof(float);
  size_t base = 4096 + (size_t)2 * B_DIM * H_DIM * sizeof(float);
  size_t need_f32 = base + (size_t)M_DIM * G_DIM * sizeof(float);

  hipMemsetAsync(d_ws, 0, 4096, stream);  // zero arrival slots

  dim3 gridA(M_DIM / 64, G_DIM / 64);
  size_t ldsB = (size_t)(512 * 64 + BPGRP * HL_STRIDE + 512 + 128) * sizeof(float);

  if (ws_size >= need_f32) {
    xproj_gemm<float><<<gridA, 256, 0, stream>>>(inputs, W_ih, b_ih, b_hh, (float*)xp);
    lstm_seq<float><<<NBLK, NTHR, ldsB, stream>>>((const float*)xp, maskp, h0, W_hh,
                                                  out, hbuf, slot_base);
  } else {
    xproj_gemm<__hip_bfloat16><<<gridA, 256, 0, stream>>>(inputs, W_ih, b_ih, b_hh,
                                                          (__hip_bfloat16*)xp);
    lstm_seq<__hip_bfloat16><<<NBLK, NTHR, ldsB, stream>>>((const __hip_bfloat16*)xp, maskp,
                                                           h0, W_hh, out, hbuf, slot_base);
  }
  (void)in_sizes; (void)n_in; (void)out_size;
}

// Round 3
// 2544.987 us; speedup vs baseline: 5.5011x; 1.7619x over previous
//
#include <hip/hip_runtime.h>
#include <hip/hip_bf16.h>

// Masked LSTM, T=512 B=64 D=512 H=512.
// Phase A: x_proj = inputs @ W_ih^T + (b_ih + b_hh), fp32 VALU GEMM (bf16 out if ws tight).
// Phase B: persistent recurrence, bf16 MFMA 16x16x32. 8 groups x 32 blocks; group owns
//          8 batches (padded to M=16; matrix pipe is idle so the waste is free); block
//          owns 16 h-dims = 64 gate rows. W_hh bf16 resident in LDS (stride 520 ->
//          max 2-way bank aliasing = free). h exchanged as bf16 via L3 with RELAXED
//          AGENT-scope atomics (per-access sc1; NO agent fences -> no L2 wb/inv).
//          8 waves = 4 gate tiles (i,f,g,o) x 2 k-splits of 256; 8 dep MFMAs per wave;
//          2-way LDS reduce; 128-thread epilogue.

#define T_DIM 512
#define B_DIM 64
#define D_DIM 512
#define H_DIM 512
#define G_DIM 2048
#define M_DIM (T_DIM * B_DIM)

#define NGROUP 8
#define BPG 32
#define NBLK (NGROUP * BPG)     // 256
#define NTHR 512
#define JPB 16                  // h-dims per block
#define BPGRP 8                 // batches per group
#define WS 520                  // LDS row stride in bf16 elements (512 + 8 pad)

typedef __attribute__((ext_vector_type(8))) short short8;
typedef __attribute__((ext_vector_type(4))) float float4v;

#define AT_LD_U(p)    __hip_atomic_load((p), __ATOMIC_RELAXED, __HIP_MEMORY_SCOPE_AGENT)
#define AT_ST_U(p, v) __hip_atomic_store((p), (v), __ATOMIC_RELAXED, __HIP_MEMORY_SCOPE_AGENT)
#define AT_LD_I(p)    __hip_atomic_load((p), __ATOMIC_RELAXED, __HIP_MEMORY_SCOPE_AGENT)
#define AT_ST_I(p, v) __hip_atomic_store((p), (v), __ATOMIC_RELAXED, __HIP_MEMORY_SCOPE_AGENT)

__device__ __forceinline__ float sigf(float x) { return 1.0f / (1.0f + __expf(-x)); }
__device__ __forceinline__ float tanhfast(float x) { return 2.0f / (1.0f + __expf(-2.0f * x)) - 1.0f; }
__device__ __forceinline__ unsigned short f2bf(float x) {
  unsigned u = __builtin_bit_cast(unsigned, x);
  return (unsigned short)((u + 0x7fffu + ((u >> 16) & 1u)) >> 16);
}

// ---------------------------------------------------------------- Phase A (unchanged)
template <typename OUT>
__global__ __launch_bounds__(256) void xproj_gemm(
    const float* __restrict__ A, const float* __restrict__ W,
    const float* __restrict__ b1, const float* __restrict__ b2,
    OUT* __restrict__ C) {
  __shared__ __align__(16) float As[16][68];
  __shared__ __align__(16) float Bs[16][68];
  const int tid = threadIdx.x;
  const int bm = blockIdx.x, bn = blockIdx.y;
  const int lr = tid >> 2, lk = tid & 3;
  const int tx = tid & 15, ty = tid >> 4;
  const float* Ap = A + (size_t)(bm * 64 + lr) * D_DIM + lk * 4;
  const float* Wp = W + (size_t)(bn * 64 + lr) * D_DIM + lk * 4;
  float acc[4][4] = {};
  for (int k0 = 0; k0 < D_DIM; k0 += 16) {
    float4 av = *(const float4*)(Ap + k0);
    float4 wv = *(const float4*)(Wp + k0);
    __syncthreads();
    As[lk * 4 + 0][lr] = av.x; As[lk * 4 + 1][lr] = av.y;
    As[lk * 4 + 2][lr] = av.z; As[lk * 4 + 3][lr] = av.w;
    Bs[lk * 4 + 0][lr] = wv.x; Bs[lk * 4 + 1][lr] = wv.y;
    Bs[lk * 4 + 2][lr] = wv.z; Bs[lk * 4 + 3][lr] = wv.w;
    __syncthreads();
#pragma unroll
    for (int kk = 0; kk < 16; ++kk) {
      float4 a = *(const float4*)&As[kk][ty * 4];
      float4 b = *(const float4*)&Bs[kk][tx * 4];
      acc[0][0] += a.x * b.x; acc[0][1] += a.x * b.y; acc[0][2] += a.x * b.z; acc[0][3] += a.x * b.w;
      acc[1][0] += a.y * b.x; acc[1][1] += a.y * b.y; acc[1][2] += a.y * b.z; acc[1][3] += a.y * b.w;
      acc[2][0] += a.z * b.x; acc[2][1] += a.z * b.y; acc[2][2] += a.z * b.z; acc[2][3] += a.z * b.w;
      acc[3][0] += a.w * b.x; acc[3][1] += a.w * b.y; acc[3][2] += a.w * b.z; acc[3][3] += a.w * b.w;
    }
  }
  const int gm = bm * 64 + ty * 4;
  const int gn = bn * 64 + tx * 4;
  float4 bv1 = *(const float4*)&b1[gn];
  float4 bv2 = *(const float4*)&b2[gn];
  float bias0 = bv1.x + bv2.x, bias1 = bv1.y + bv2.y, bias2 = bv1.z + bv2.z, bias3 = bv1.w + bv2.w;
#pragma unroll
  for (int i = 0; i < 4; ++i) {
    OUT* cp = C + (size_t)(gm + i) * G_DIM + gn;
    cp[0] = (OUT)(acc[i][0] + bias0);
    cp[1] = (OUT)(acc[i][1] + bias1);
    cp[2] = (OUT)(acc[i][2] + bias2);
    cp[3] = (OUT)(acc[i][3] + bias3);
  }
}

// ---------------------------------------------------------------- group barrier
__device__ __forceinline__ void gbarrier(int* slots, int rank, int target) {
  __syncthreads();   // drains vmcnt(0): this block's sc1 stores are at the coherence point
  const int tid = threadIdx.x;
  if (tid == 0) AT_ST_I(&slots[rank], target);
  if (tid < 64) {
    int v;
    do {
      v = (tid < BPG) ? AT_LD_I(&slots[tid]) : target;
      if (__all(v >= target)) break;
      __builtin_amdgcn_s_sleep(2);
    } while (true);
  }
  __syncthreads();
  __asm__ volatile("" ::: "memory");
}

// ---------------------------------------------------------------- Phase B (MFMA)
template <typename XP>
__global__ __launch_bounds__(NTHR) void lstm_seq(
    const XP* __restrict__ xproj, const float* __restrict__ mask,
    const float* __restrict__ h0, const float* __restrict__ Whh,
    float* __restrict__ out, unsigned short* __restrict__ hbuf,
    int* slot_base) {
  extern __shared__ char smemc[];
  unsigned short* Wl = (unsigned short*)smemc;     // [r][k] 64 x WS bf16 = 66560 B
  unsigned short* hl = Wl + 64 * WS;               // [m][k] 16 x WS bf16 = 16640 B (m>=8 garbage)
  float* part = (float*)(hl + 16 * WS);            // 8 waves x 256 f32 = 8192 B
  float* gl = part + 2048;                         // [b][r] 8 x 64 f32 = 2048 B
  float* cl = gl + 512;                            // 128 f32

  const int tid = threadIdx.x;
  const int blk = blockIdx.x;
  const int grp = blk & 7;
  const int rank = blk >> 3;
  const int bbase = grp * BPGRP;
  const int jbase = rank * JPB;
  int* slots = (int*)((char*)slot_base + grp * 128);

  // W_hh slice -> LDS bf16. r = q*16 + jl <-> global row q*512 + jbase + jl.
  for (int idx = tid; idx < 64 * 128; idx += NTHR) {
    int r = idx >> 7;
    int k4 = (idx & 127) << 2;
    int grow = (r >> 4) * H_DIM + jbase + (r & 15);
    float4 w = *(const float4*)(Whh + (size_t)grow * H_DIM + k4);
    unsigned lo = (unsigned)f2bf(w.x) | ((unsigned)f2bf(w.y) << 16);
    unsigned hi = (unsigned)f2bf(w.z) | ((unsigned)f2bf(w.w) << 16);
    *(uint2*)(Wl + r * WS + k4) = make_uint2(lo, hi);
  }

  const int eb = tid >> 4, ejl = tid & 15;   // tid<128: (batch 0..7, h-dim 0..15)
  float h0v = 0.0f, c0v = 0.0f;
  if (tid < 128) {
    int bglob = bbase + eb;
    int jglob = jbase + ejl;
    h0v = h0[bglob * H_DIM + jglob];
    c0v = h0v;
    cl[tid] = c0v;
  }
  // publish h0 as bf16 into buffer 0 (pack pairs via shfl; waves 0,1 fully active)
  {
    int mybits = (tid < 128) ? (int)f2bf(h0v) : 0;
    int nb = __shfl_down(mybits, 1, 64);
    if (tid < 128 && ((ejl & 1) == 0)) {
      unsigned pk = (unsigned)mybits | ((unsigned)nb << 16);
      AT_ST_U((unsigned*)hbuf + (bbase + eb) * 256 + ((jbase + ejl) >> 1), pk);
    }
  }
  gbarrier(slots, rank, 1);

  const int w = tid >> 6;        // wave id
  const int lane = tid & 63;
  const int q = w & 3;           // gate tile (i,f,g,o)
  const int ks = w >> 2;         // k-split 0..1 (256 k each)
  const int am = lane & 15;      // A row (batch, padded to 16)
  const int koct = (lane >> 4) * 8;
  const int br = q * 16 + (lane & 15);   // W row in LDS

  for (int ts = 0; ts < T_DIM; ++ts) {
    const unsigned* cur32 = (const unsigned*)(hbuf + (ts & 1) * (B_DIM * H_DIM));
    unsigned* nxt32 = (unsigned*)(hbuf + ((ts + 1) & 1) * (B_DIM * H_DIM));

    // stage h (8 batches x 512 bf16 = 8KB) from L3 into LDS [m][k]
#pragma unroll
    for (int i = 0; i < 4; ++i) {
      int idx = tid + i * NTHR;
      int b = idx >> 8;          // 0..7
      int ku = idx & 255;        // uint (=2 bf16) index within row
      unsigned u = AT_LD_U((unsigned*)&cur32[(bbase + b) * 256 + ku]);
      ((unsigned*)hl)[b * (WS / 2) + ku] = u;
    }
    // x_proj + mask prefetch (consumed in epilogue, well overlapped)
    float xpv0 = 0.f, xpv1 = 0.f, xpv2 = 0.f, xpv3 = 0.f, mval = 1.f;
    if (tid < 128) {
      int bglob = bbase + eb;
      const XP* xb = xproj + ((size_t)ts * B_DIM + bglob) * G_DIM + jbase + ejl;
      xpv0 = (float)xb[0];
      xpv1 = (float)xb[512];
      xpv2 = (float)xb[1024];
      xpv3 = (float)xb[1536];
      mval = mask[ts * B_DIM + bglob];
    }
    __syncthreads();

    // MFMA: D[m][n] = sum_k h[m][k] * W[q*16+n][k] over this wave's 256-k slice
    float4v acc = {0.f, 0.f, 0.f, 0.f};
#pragma unroll
    for (int kc = 0; kc < 8; ++kc) {
      int k = ks * 256 + kc * 32 + koct;
      short8 a = *(const short8*)(hl + am * WS + k);
      short8 b8 = *(const short8*)(Wl + br * WS + k);
      acc = __builtin_amdgcn_mfma_f32_16x16x32_bf16(a, b8, acc, 0, 0, 0);
    }
    // partials -> LDS (part doesn't alias hl): part[w][m][n]
#pragma unroll
    for (int reg = 0; reg < 4; ++reg) {
      int m = (lane >> 4) * 4 + reg;
      part[w * 256 + m * 16 + (lane & 15)] = acc[reg];
    }
    __syncthreads();
    // reduce the 2 k-splits -> gl[b][r]; only b<8 matter
    {
      int q2 = tid >> 7, m2 = (tid >> 4) & 7, n2 = tid & 15;
      float s = part[q2 * 256 + m2 * 16 + n2] + part[(q2 + 4) * 256 + m2 * 16 + n2];
      gl[m2 * 64 + q2 * 16 + n2] = s;
    }
    __syncthreads();

    float h_new = 0.f;
    if (tid < 128) {
      float iv = sigf(gl[eb * 64 + ejl] + xpv0);
      float fv = sigf(gl[eb * 64 + 16 + ejl] + xpv1);
      float gv = tanhfast(gl[eb * 64 + 32 + ejl] + xpv2);
      float ov = sigf(gl[eb * 64 + 48 + ejl] + xpv3);
      float c_old = cl[tid];
      float c_new = fv * c_old + iv * gv;
      h_new = ov * tanhfast(c_new);
      h_new = h_new * mval + h0v * (1.0f - mval);
      c_new = c_new * mval + c0v * (1.0f - mval);
      cl[tid] = c_new;
      int bglob = bbase + eb;
      int jglob = jbase + ejl;
      out[((size_t)ts * B_DIM + bglob) * H_DIM + jglob] = h_new;
      if (ts == T_DIM - 1) {
        out[(size_t)T_DIM * B_DIM * H_DIM + bglob * H_DIM + jglob] = h_new;
        out[(size_t)T_DIM * B_DIM * H_DIM + B_DIM * H_DIM + bglob * H_DIM + jglob] = c_new;
      }
    }
    // publish h_new as packed bf16 pairs (even-jl lanes store a uint)
    {
      int mybits = (tid < 128) ? (int)f2bf(h_new) : 0;
      int nb = __shfl_down(mybits, 1, 64);
      if (tid < 128 && ((ejl & 1) == 0)) {
        unsigned pk = (unsigned)mybits | ((unsigned)nb << 16);
        AT_ST_U(&nxt32[(bbase + eb) * 256 + ((jbase + ejl) >> 1)], pk);
      }
    }
    gbarrier(slots, rank, ts + 2);
  }
}

// ---------------------------------------------------------------- launch
extern "C" void kernel_launch(void* const* d_in, const int* in_sizes, int n_in,
                              void* d_out, int out_size, void* d_ws, size_t ws_size,
                              hipStream_t stream) {
  const float* inputs = (const float*)d_in[0];
  const float* maskp  = (const float*)d_in[1];
  const float* h0     = (const float*)d_in[2];
  const float* W_ih   = (const float*)d_in[3];
  const float* W_hh   = (const float*)d_in[4];
  const float* b_ih   = (const float*)d_in[5];
  const float* b_hh   = (const float*)d_in[6];
  float* out = (float*)d_out;

  char* ws = (char*)d_ws;
  int* slot_base = (int*)ws;                            // 8 groups x 32 slots (128B apart)
  unsigned short* hbuf = (unsigned short*)(ws + 4096);  // bf16 h double buffer, 128KB
  char* xp = ws + 4096 + 2 * (size_t)B_DIM * H_DIM * sizeof(unsigned short);
  size_t base = 4096 + 2 * (size_t)B_DIM * H_DIM * sizeof(unsigned short);
  size_t need_f32 = base + (size_t)M_DIM * G_DIM * sizeof(float);

  hipMemsetAsync(d_ws, 0, 4096, stream);

  dim3 gridA(M_DIM / 64, G_DIM / 64);
  size_t ldsB = (size_t)(64 * WS * 2 + 16 * WS * 2 + 2048 * 4 + 512 * 4 + 128 * 4);  // 93952 B

  if (ws_size >= need_f32) {
    xproj_gemm<float><<<gridA, 256, 0, stream>>>(inputs, W_ih, b_ih, b_hh, (float*)xp);
    lstm_seq<float><<<NBLK, NTHR, ldsB, stream>>>((const float*)xp, maskp, h0, W_hh,
                                                  out, hbuf, slot_base);
  } else {
    xproj_gemm<__hip_bfloat16><<<gridA, 256, 0, stream>>>(inputs, W_ih, b_ih, b_hh,
                                                          (__hip_bfloat16*)xp);
    lstm_seq<__hip_bfloat16><<<NBLK, NTHR, ldsB, stream>>>((const __hip_bfloat16*)xp, maskp,
                                                           h0, W_hh, out, hbuf, slot_base);
  }
  (void)in_sizes; (void)n_in; (void)out_size;
}